// Round 2
// baseline (597.841 us; speedup 1.0000x reference)
//
#include <hip/hip_runtime.h>
#include <cstdint>
#include <cstddef>

#define S_LEN 2048
#define DM 512
#define NH 8
#define DK 64
#define DFF 2048
#define BATCH 2
#define NROWS (BATCH*S_LEN)   // 4096
#define BHN (BATCH*NH)        // 16

#define MASKED_L2 (-1.4426950408889634e9f)
#define QSCALE 0.18033688011112042f   // (1/sqrt(64)) * log2(e), folded into Q

typedef __attribute__((ext_vector_type(8))) _Float16 f16x8;
typedef __attribute__((ext_vector_type(4))) float f32x4;

#define MFMA(a,b,c) __builtin_amdgcn_mfma_f32_16x16x32_f16(a,b,c,0,0,0)

__device__ __forceinline__ unsigned short f2h(float x){
  union{ _Float16 h; unsigned short u; } c; c.h = (_Float16)x; return c.u;
}
// XOR swizzle on 16B granules; rows of 64 halves
__device__ __forceinline__ int sw64(int r, int c){
  return r*64 + ((((c>>3) ^ r) & 7)<<3) + (c&7);
}

typedef const __attribute__((address_space(1))) uint32_t* gas1;
typedef __attribute__((address_space(3))) uint32_t* las3;
__device__ __forceinline__ void gl_lds16(const unsigned short* g, unsigned short* l){
  __builtin_amdgcn_global_load_lds((gas1)(const void*)g, (las3)(void*)l, 16, 0, 0);
}

// ---------------------------------------------------------------------------
// prep: z=0..5 transpose+fp16 weights, z=6 x->fp16, z=7 mask bit-pack
// grid (1024, 8), block 256
// ---------------------------------------------------------------------------
__global__ __launch_bounds__(256) void prep_kernel(
    const float* __restrict__ x, const int* __restrict__ mask,
    const float* __restrict__ Wq, const float* __restrict__ Wk,
    const float* __restrict__ Wv, const float* __restrict__ Wo,
    const float* __restrict__ W1, const float* __restrict__ W2,
    unsigned short* __restrict__ xb,
    unsigned short* __restrict__ wqkvT, unsigned short* __restrict__ woT,
    unsigned short* __restrict__ w1T,   unsigned short* __restrict__ w2T,
    unsigned* __restrict__ maskw)
{
  const int z = blockIdx.y;
  const int t = blockIdx.x;
  const int tid = threadIdx.x;
  if (z < 6){
    const float* W; unsigned short* WT; int K, N;
    switch(z){
      case 0: W=Wq; WT=wqkvT;            K=512;  N=512;  break;
      case 1: W=Wk; WT=wqkvT+512*512;    K=512;  N=512;  break;
      case 2: W=Wv; WT=wqkvT+2*512*512;  K=512;  N=512;  break;
      case 3: W=Wo; WT=woT;              K=512;  N=512;  break;
      case 4: W=W1; WT=w1T;              K=512;  N=2048; break;
      default:W=W2; WT=w2T;              K=2048; N=512;  break;
    }
    const int ntiles = N>>5, ktiles = K>>5;
    if (t >= ntiles*ktiles) return;
    const int kt = t / ntiles, nt = t - kt*ntiles;
    __shared__ float tile[32][33];
    const int tx = tid & 31, ty = tid >> 5;
    #pragma unroll
    for (int i=0;i<4;i++){
      int r = ty + i*8;
      tile[r][tx] = W[(size_t)(kt*32 + r)*N + nt*32 + tx];
    }
    __syncthreads();
    #pragma unroll
    for (int i=0;i<4;i++){
      int r = ty + i*8;
      WT[(size_t)(nt*32 + r)*K + kt*32 + tx] = f2h(tile[tx][r]);
    }
  } else if (z == 6){
    size_t base = (size_t)t*2048 + (size_t)tid*8;
    float4 a = *(const float4*)(x + base);
    float4 b = *(const float4*)(x + base + 4);
    union{ unsigned short h[8]; uint4 v; } pk;
    pk.h[0]=f2h(a.x); pk.h[1]=f2h(a.y); pk.h[2]=f2h(a.z); pk.h[3]=f2h(a.w);
    pk.h[4]=f2h(b.x); pk.h[5]=f2h(b.y); pk.h[6]=f2h(b.z); pk.h[7]=f2h(b.w);
    *(uint4*)(xb + base) = pk.v;
  } else {
    if (t >= 512) return;
    const int gid = t*256 + tid;             // 0..131071
    const int row = gid >> 6, w = gid & 63;
    const int4* mp = (const int4*)(mask + (size_t)row*2048 + w*32);
    unsigned word = 0;
    #pragma unroll
    for (int j=0;j<8;j++){
      int4 v = mp[j];
      word |= (unsigned)(v.x!=0) << (j*4+0);
      word |= (unsigned)(v.y!=0) << (j*4+1);
      word |= (unsigned)(v.z!=0) << (j*4+2);
      word |= (unsigned)(v.w!=0) << (j*4+3);
    }
    maskw[gid] = word;
  }
}

// ---------------------------------------------------------------------------
// GEMM (m97 structure): C[BMxBN] = A[M,KD] @ BT[N,KD]^T, fp16 in, fp32 acc.
// global_load_lds width-16 staging, single LDS buffer, 2 barriers per k-step,
// 16 (or 8) MFMA per barrier pair.
// EPI 0: QKV fused (col 0..1535 -> q/k/v, Q scaled), out fp16 [bh,s,d]
// EPI 1: out fp32 = acc + bias[col] + resid[row,col]   (N=512)
// EPI 2: out fp16 = gelu(acc + bias[col])              (N=2048)
// ---------------------------------------------------------------------------
template<int BM, int BN, int KD, int EPI>
__global__ __launch_bounds__(256) void gemm2(
    const unsigned short* __restrict__ A,
    const unsigned short* __restrict__ BT,
    const float* __restrict__ bias,
    const float* __restrict__ resid,
    float* __restrict__ outf,
    unsigned short* __restrict__ outq,
    unsigned short* __restrict__ outk,
    unsigned short* __restrict__ outv)
{
  constexpr int WGM = (BM >= 128) ? 2 : 1;
  constexpr int WGN = 4 / WGM;
  constexpr int WTM = BM / WGM;
  constexpr int WTN = BN / WGN;
  constexpr int MT = WTM / 16;
  constexpr int NT = WTN / 16;
  constexpr int NKS = KD / 32;
  constexpr int AISS = (BM*4)/256;   // 16B chunks per thread, A tile
  constexpr int BISS = (BN*4)/256;
  __shared__ __align__(16) unsigned short As[BM*32];
  __shared__ __align__(16) unsigned short Bs[BN*32];
  const int tid = threadIdx.x, wid = tid>>6, l = tid&63, quad = l>>4, lc = l&15;
  const int m0 = blockIdx.x*BM, n0 = blockIdx.y*BN;
  const int wm = (WGM==2) ? (wid&1) : 0;
  const int wn = (WGM==2) ? (wid>>1) : wid;
  f32x4 acc[MT][NT] = {};
  for (int kk=0; kk<NKS; kk++){
    #pragma unroll
    for (int i=0;i<AISS;i++){
      const int ch = i*256 + tid;
      gl_lds16(A + (size_t)(m0 + (ch>>2))*KD + kk*32 + (ch&3)*8,
               &As[(i*256 + wid*64)*8]);
    }
    #pragma unroll
    for (int i=0;i<BISS;i++){
      const int ch = i*256 + tid;
      gl_lds16(BT + (size_t)(n0 + (ch>>2))*KD + kk*32 + (ch&3)*8,
               &Bs[(i*256 + wid*64)*8]);
    }
    __syncthreads();
    f16x8 af[MT], bf[NT];
    #pragma unroll
    for (int i=0;i<MT;i++)
      af[i] = *(const f16x8*)&As[(wm*WTM + i*16 + lc)*32 + quad*8];
    #pragma unroll
    for (int j=0;j<NT;j++)
      bf[j] = *(const f16x8*)&Bs[(wn*WTN + j*16 + lc)*32 + quad*8];
    #pragma unroll
    for (int i=0;i<MT;i++)
      #pragma unroll
      for (int j=0;j<NT;j++)
        acc[i][j] = MFMA(af[i], bf[j], acc[i][j]);
    __syncthreads();
  }
  #pragma unroll
  for (int i=0;i<MT;i++){
    const int row0 = m0 + wm*WTM + i*16 + quad*4;
    #pragma unroll
    for (int j=0;j<NT;j++){
      const int col = n0 + wn*WTN + j*16 + lc;
      f32x4 v = acc[i][j];
      #pragma unroll
      for (int r=0;r<4;r++){
        const int row = row0 + r;
        const float val = v[r];
        if (EPI == 0){
          const int z = col>>9, cw = col&511, h = cw>>6, d = cw&63;
          const int b = row>>11, s = row&2047;
          unsigned short* dst = (z==0)?outq:(z==1)?outk:outv;
          const float sc = (z==0)?QSCALE:1.0f;
          dst[(((size_t)(b*NH + h))*S_LEN + s)*DK + d] = f2h(val*sc);
        } else if (EPI == 1){
          const size_t idx = (size_t)row*DM + col;
          outf[idx] = val + bias[col] + resid[idx];
        } else {
          const float xx = val + bias[col];
          const float gg = 0.5f*xx*(1.0f + erff(xx*0.70710678118654752f));
          outq[(size_t)row*DFF + col] = f2h(gg);
        }
      }
    }
  }
}

// ---------------------------------------------------------------------------
// V transpose: v_ws[bh][s][64] -> vT[bh][64][2048]. grid (32,16), block 256
// ---------------------------------------------------------------------------
__global__ __launch_bounds__(256) void vtrans_kernel(
    const unsigned short* __restrict__ v, unsigned short* __restrict__ vt)
{
  __shared__ unsigned short t[64][66];
  const int bh = blockIdx.y, s0 = blockIdx.x*64;
  const int tid = threadIdx.x;
  #pragma unroll
  for (int i=0;i<2;i++){
    const int idx = tid + i*256;            // 512 chunks of 8 halves
    const int row = idx>>3, col = (idx&7)*8;
    *(uint4*)&t[row][col] =
      *(const uint4*)(v + ((size_t)bh*S_LEN + s0 + row)*DK + col);
  }
  __syncthreads();
  #pragma unroll
  for (int i=0;i<2;i++){
    const int idx = tid + i*256;
    const int d = idx>>3, sc = (idx&7)*8;
    union{ unsigned short h[8]; uint4 u; } pk;
    #pragma unroll
    for (int j=0;j<8;j++) pk.h[j] = t[sc+j][d];
    *(uint4*)(vt + ((size_t)bh*DK + d)*S_LEN + s0 + sc) = pk.u;
  }
}

// ---------------------------------------------------------------------------
// Fused attention: per-wave (16 q-rows), no barriers.
// Pass A: QK^T -> (m, 1/l) in registers.  Pass B: recompute QK^T, write
// normalized probs (nontemporal fp32) + fused P@V via per-wave LDS P buffer.
// K and V^T fragments loaded directly from global (contiguous in k).
// grid (32, 16), block 256 (4 independent waves)
// ---------------------------------------------------------------------------
__global__ __launch_bounds__(256) void attn_fused(
    const unsigned short* __restrict__ qw,
    const unsigned short* __restrict__ kw,
    const unsigned short* __restrict__ vt,
    const unsigned* __restrict__ maskw,
    float* __restrict__ attn,
    unsigned short* __restrict__ ctx)
{
  const int bh = blockIdx.y;
  const int tid = threadIdx.x, wid = tid>>6, l = tid&63, quad = l>>4, lc = l&15;
  const int q0 = blockIdx.x*64 + wid*16;
  __shared__ __align__(16) unsigned short Pbuf[4][16*64];
  unsigned short* myP = Pbuf[wid];
  const unsigned short* qb = qw + ((size_t)bh*S_LEN + q0)*DK;
  const unsigned short* kb = kw + (size_t)bh*S_LEN*DK;
  const unsigned short* vb = vt + (size_t)bh*DK*S_LEN;
  const f16x8 aQ0 = *(const f16x8*)(qb + (size_t)lc*DK + quad*8);
  const f16x8 aQ1 = *(const f16x8*)(qb + (size_t)lc*DK + 32 + quad*8);
  const int rowb = q0 + quad*4;

  float m[4]  = {-3e38f,-3e38f,-3e38f,-3e38f};
  float ls[4] = {0.f,0.f,0.f,0.f};

  // ---- pass A: softmax stats, K-frag prefetch rotation
  f16x8 nb0[4], nb1[4];
  #pragma unroll
  for (int nt=0;nt<4;nt++){
    const unsigned short* kp = kb + (size_t)(nt*16+lc)*DK;
    nb0[nt] = *(const f16x8*)(kp + quad*8);
    nb1[nt] = *(const f16x8*)(kp + 32 + quad*8);
  }
  for (int c=0;c<32;c++){
    f16x8 cb0[4], cb1[4];
    #pragma unroll
    for (int nt=0;nt<4;nt++){ cb0[nt]=nb0[nt]; cb1[nt]=nb1[nt]; }
    if (c+1 < 32){
      #pragma unroll
      for (int nt=0;nt<4;nt++){
        const unsigned short* kp = kb + (size_t)((c+1)*64 + nt*16+lc)*DK;
        nb0[nt] = *(const f16x8*)(kp + quad*8);
        nb1[nt] = *(const f16x8*)(kp + 32 + quad*8);
      }
    }
    uint2 mw[4];
    #pragma unroll
    for (int r=0;r<4;r++)
      mw[r] = *(const uint2*)(maskw + (size_t)(rowb+r)*64 + c*2);
    float sv[4][4];
    #pragma unroll
    for (int nt=0;nt<4;nt++){
      f32x4 s = {0,0,0,0};
      s = MFMA(aQ0, cb0[nt], s);
      s = MFMA(aQ1, cb1[nt], s);
      const int sh = (nt&1)*16 + lc;
      #pragma unroll
      for (int r=0;r<4;r++){
        const unsigned w = (nt<2) ? mw[r].x : mw[r].y;
        sv[nt][r] = ((w>>sh)&1u) ? s[r] : MASKED_L2;
      }
    }
    #pragma unroll
    for (int r=0;r<4;r++){
      const float mc = fmaxf(fmaxf(sv[0][r],sv[1][r]), fmaxf(sv[2][r],sv[3][r]));
      const float m2 = fmaxf(m[r], mc);
      ls[r] = ls[r]*__builtin_exp2f(m[r]-m2)
            + __builtin_exp2f(sv[0][r]-m2) + __builtin_exp2f(sv[1][r]-m2)
            + __builtin_exp2f(sv[2][r]-m2) + __builtin_exp2f(sv[3][r]-m2);
      m[r] = m2;
    }
  }
  #pragma unroll
  for (int o=1;o<16;o<<=1){
    #pragma unroll
    for (int r=0;r<4;r++){
      const float mo = __shfl_xor(m[r], o, 64);
      const float lo = __shfl_xor(ls[r], o, 64);
      const float m2 = fmaxf(m[r], mo);
      ls[r] = ls[r]*__builtin_exp2f(m[r]-m2) + lo*__builtin_exp2f(mo-m2);
      m[r] = m2;
    }
  }
  float li[4];
  #pragma unroll
  for (int r=0;r<4;r++) li[r] = 1.0f/ls[r];

  // ---- pass B: probs + P@V
  f32x4 O[4] = {{0,0,0,0},{0,0,0,0},{0,0,0,0},{0,0,0,0}};
  float* ab = attn + (size_t)bh*S_LEN*S_LEN;
  for (int c=0;c<32;c++){
    uint2 mw[4];
    #pragma unroll
    for (int r=0;r<4;r++)
      mw[r] = *(const uint2*)(maskw + (size_t)(rowb+r)*64 + c*2);
    #pragma unroll
    for (int nt=0;nt<4;nt++){
      const unsigned short* kp = kb + (size_t)(c*64 + nt*16+lc)*DK;
      f16x8 b0 = *(const f16x8*)(kp + quad*8);
      f16x8 b1 = *(const f16x8*)(kp + 32 + quad*8);
      f32x4 s = {0,0,0,0};
      s = MFMA(aQ0, b0, s);
      s = MFMA(aQ1, b1, s);
      const int sh = (nt&1)*16 + lc;
      #pragma unroll
      for (int r=0;r<4;r++){
        const unsigned w = (nt<2) ? mw[r].x : mw[r].y;
        const float se = ((w>>sh)&1u) ? s[r] : MASKED_L2;
        const float p  = __builtin_exp2f(se - m[r]) * li[r];
        __builtin_nontemporal_store(p,
          ab + (size_t)(rowb+r)*S_LEN + (size_t)c*64 + nt*16 + lc);
        myP[sw64(quad*4+r, nt*16+lc)] = f2h(p);
      }
    }
    #pragma unroll
    for (int ks=0;ks<2;ks++){
      f16x8 aP = *(const f16x8*)&myP[sw64(lc, ks*32 + quad*8)];
      #pragma unroll
      for (int dt=0;dt<4;dt++){
        f16x8 vv = *(const f16x8*)(vb + (size_t)(dt*16+lc)*S_LEN + c*64 + ks*32 + quad*8);
        O[dt] = MFMA(aP, vv, O[dt]);
      }
    }
  }
  const int b = bh>>3, h = bh&7;
  #pragma unroll
  for (int dt=0;dt<4;dt++){
    #pragma unroll
    for (int r=0;r<4;r++)
      ctx[((size_t)b*S_LEN + rowb + r)*DM + h*DK + dt*16 + lc] = f2h(O[dt][r]);
  }
}

// ---------------------------------------------------------------------------
// LayerNorm over D=512; one wave per row; optional fp16 copy
// ---------------------------------------------------------------------------
__global__ __launch_bounds__(256) void ln_kernel(
    const float* __restrict__ in, const float* __restrict__ g,
    const float* __restrict__ b, float* __restrict__ outf,
    unsigned short* __restrict__ outb)
{
  const int row = blockIdx.x*4 + (threadIdx.x>>6);
  const int l = threadIdx.x & 63;
  const float* p = in + (size_t)row*DM + l*8;
  float4 v0 = *(const float4*)p;
  float4 v1 = *(const float4*)(p+4);
  float vals[8] = {v0.x,v0.y,v0.z,v0.w,v1.x,v1.y,v1.z,v1.w};
  float s = 0.f, q = 0.f;
  #pragma unroll
  for (int j=0;j<8;j++){ s += vals[j]; q += vals[j]*vals[j]; }
  #pragma unroll
  for (int o=1;o<64;o<<=1){ s += __shfl_xor(s,o,64); q += __shfl_xor(q,o,64); }
  const float mu = s*(1.0f/DM);
  const float var = q*(1.0f/DM) - mu*mu;
  const float rs = rsqrtf(var + 1e-6f);
  const float* gp = g + l*8;
  const float* bp = b + l*8;
  float4 g0 = *(const float4*)gp, g1 = *(const float4*)(gp+4);
  float4 bb0 = *(const float4*)bp, bb1 = *(const float4*)(bp+4);
  float gv[8] = {g0.x,g0.y,g0.z,g0.w,g1.x,g1.y,g1.z,g1.w};
  float bv[8] = {bb0.x,bb0.y,bb0.z,bb0.w,bb1.x,bb1.y,bb1.z,bb1.w};
  float ov[8];
  #pragma unroll
  for (int j=0;j<8;j++) ov[j] = (vals[j]-mu)*rs*gv[j] + bv[j];
  float* op = outf + (size_t)row*DM + l*8;
  *(float4*)op     = make_float4(ov[0],ov[1],ov[2],ov[3]);
  *(float4*)(op+4) = make_float4(ov[4],ov[5],ov[6],ov[7]);
  if (outb){
    union{ unsigned short h[8]; uint4 v; } pk;
    #pragma unroll
    for (int j=0;j<8;j++) pk.h[j] = f2h(ov[j]);
    *(uint4*)(outb + (size_t)row*DM + l*8) = pk.v;
  }
}

// ---------------------------------------------------------------------------
extern "C" void kernel_launch(void* const* d_in, const int* in_sizes, int n_in,
                              void* d_out, int out_size, void* d_ws, size_t ws_size,
                              hipStream_t stream)
{
  const float* x    = (const float*)d_in[0];
  // d_in[1] sensor_weights, d_in[8] sensor_attention, d_in[9] temporal_bias:
  // constant along the softmax axis -> exactly cancel in softmax; unused.
  const int*   mask = (const int*)d_in[2];
  const float* Wq   = (const float*)d_in[3];
  const float* Wk   = (const float*)d_in[4];
  const float* Wv   = (const float*)d_in[5];
  const float* Wo   = (const float*)d_in[6];
  const float* bo   = (const float*)d_in[7];
  const float* ln1g = (const float*)d_in[10];
  const float* ln1b = (const float*)d_in[11];
  const float* ln2g = (const float*)d_in[12];
  const float* ln2b = (const float*)d_in[13];
  const float* W1   = (const float*)d_in[14];
  const float* b1   = (const float*)d_in[15];
  const float* W2   = (const float*)d_in[16];
  const float* b2   = (const float*)d_in[17];

  float* x2_out   = (float*)d_out;
  float* attn_out = x2_out + (size_t)NROWS*DM;

  char* p = (char*)d_ws;
  auto alloc = [&](size_t bytes)->char*{
    char* r = p; p += (bytes + 255) & ~(size_t)255; return r;
  };
  unsigned short* xb    = (unsigned short*)alloc((size_t)NROWS*DM*2);
  unsigned short* wqkvT = (unsigned short*)alloc((size_t)3*512*512*2);
  unsigned short* woT   = (unsigned short*)alloc(512*512*2);
  unsigned short* w1T   = (unsigned short*)alloc(2048*512*2);
  unsigned short* w2T   = (unsigned short*)alloc(512*2048*2);
  unsigned short* q_ws  = (unsigned short*)alloc((size_t)BHN*S_LEN*DK*2);
  unsigned short* k_ws  = (unsigned short*)alloc((size_t)BHN*S_LEN*DK*2);
  unsigned short* v_ws  = (unsigned short*)alloc((size_t)BHN*S_LEN*DK*2);
  unsigned short* vT    = (unsigned short*)alloc((size_t)BHN*DK*S_LEN*2);
  unsigned*       maskw = (unsigned*)alloc((size_t)S_LEN*64*4);
  unsigned short* ctxb  = (unsigned short*)alloc((size_t)NROWS*DM*2);
  float*          yv    = (float*)alloc((size_t)NROWS*DM*4);
  float*          x1f   = (float*)alloc((size_t)NROWS*DM*4);
  unsigned short* x1b   = (unsigned short*)alloc((size_t)NROWS*DM*2);
  unsigned short* hb    = (unsigned short*)alloc((size_t)NROWS*DFF*2);
  float*          zv    = (float*)alloc((size_t)NROWS*DM*4);

  // 1. prep
  prep_kernel<<<dim3(1024,8), 256, 0, stream>>>(
      x, mask, Wq, Wk, Wv, Wo, W1, W2,
      xb, wqkvT, woT, w1T, w2T, maskw);

  // 2. fused QKV projection (N=1536)
  gemm2<128,128,512,0><<<dim3(32,12), 256, 0, stream>>>(
      xb, wqkvT, nullptr, nullptr, nullptr, q_ws, k_ws, v_ws);

  // 3. V transpose for PV B-operand
  vtrans_kernel<<<dim3(32,16), 256, 0, stream>>>(v_ws, vT);

  // 4. fused attention (stats + probs + P@V, no barriers)
  attn_fused<<<dim3(32,16), 256, 0, stream>>>(
      q_ws, k_ws, vT, maskw, attn_out, ctxb);

  // 5. output proj + bias + residual -> yv
  gemm2<64,128,512,1><<<dim3(64,4), 256, 0, stream>>>(
      ctxb, woT, bo, x, yv, nullptr, nullptr, nullptr);

  // 6. LN1 -> x1f (fp32) + x1b (fp16)
  ln_kernel<<<1024, 256, 0, stream>>>(yv, ln1g, ln1b, x1f, x1b);

  // 7. FF1 + gelu -> hb (fp16)
  gemm2<128,128,512,2><<<dim3(32,16), 256, 0, stream>>>(
      x1b, w1T, b1, nullptr, nullptr, hb, nullptr, nullptr);

  // 8. FF2 + bias + residual(x1) -> zv
  gemm2<64,128,2048,1><<<dim3(64,4), 256, 0, stream>>>(
      hb, w2T, b2, x1f, zv, nullptr, nullptr, nullptr);

  // 9. LN2 -> x2
  ln_kernel<<<1024, 256, 0, stream>>>(zv, ln2g, ln2b, x2_out, nullptr);

  (void)in_sizes; (void)n_in; (void)out_size; (void)ws_size;
}